// Round 6
// baseline (186.052 us; speedup 1.0000x reference)
//
#include <hip/hip_runtime.h>
#include <cstdint>

#define LL 2048
#define HH 16
#define DD 64
#define LSTR 1024      // H*D
#define EPSF 1e-6f
#define PAD 72         // ushorts per LDS row: 144 B = 16B-aligned
#define MAGIC 0x3C6E0B8Au
// swizzle for transposed-store tiles accessed with b128 frags
#define SWZ(row, off) ((row)*PAD + ((off) ^ ((((row)>>3)&7)<<3)))

typedef __bf16 bf16x8 __attribute__((ext_vector_type(8)));
typedef float floatx4 __attribute__((ext_vector_type(4)));
typedef unsigned short ushortx8 __attribute__((ext_vector_type(8)));
typedef unsigned short ushortx4 __attribute__((ext_vector_type(4)));
typedef unsigned short ushortx2 __attribute__((ext_vector_type(2)));

static __device__ __forceinline__ float fmap(float x){ return x > 0.f ? x + 1.f : __expf(x); }
static __device__ __forceinline__ unsigned short f2bf(float f){
    return __builtin_bit_cast(unsigned short, static_cast<__bf16>(f));   // RNE, 1 VALU op
}
static __device__ __forceinline__ float bf2f(unsigned short s){
    unsigned u = ((unsigned)s) << 16;
    return __builtin_bit_cast(float, u);
}
static __device__ __forceinline__ bf16x8 ldf(const unsigned short* p){
    return __builtin_bit_cast(bf16x8, *(const ushortx8*)p);
}

// store rows r, r+1 of an [s][d]-layout tile (bf16), optional feature map (unswizzled)
template<bool MAP>
static __device__ __forceinline__ void st_sd(unsigned short* base, int r, int c, float4 a, float4 b){
    if (MAP) {
        *(ushortx4*)(base + r*PAD + c)     = ushortx4{ f2bf(fmap(a.x)), f2bf(fmap(a.y)), f2bf(fmap(a.z)), f2bf(fmap(a.w)) };
        *(ushortx4*)(base + (r+1)*PAD + c) = ushortx4{ f2bf(fmap(b.x)), f2bf(fmap(b.y)), f2bf(fmap(b.z)), f2bf(fmap(b.w)) };
    } else {
        *(ushortx4*)(base + r*PAD + c)     = ushortx4{ f2bf(a.x), f2bf(a.y), f2bf(a.z), f2bf(a.w) };
        *(ushortx4*)(base + (r+1)*PAD + c) = ushortx4{ f2bf(b.x), f2bf(b.y), f2bf(b.z), f2bf(b.w) };
    }
}
// transposed store into a [d][s]- or [m][s]-layout tile (bf16), SWZ-swizzled
template<bool MAP>
static __device__ __forceinline__ void st_tr(unsigned short* base, int r, int c, float4 a, float4 b){
    float aa[4] = {a.x, a.y, a.z, a.w}, bb[4] = {b.x, b.y, b.z, b.w};
#pragma unroll
    for (int e = 0; e < 4; ++e) {
        float x0 = MAP ? fmap(aa[e]) : aa[e];
        float x1 = MAP ? fmap(bb[e]) : bb[e];
        *(ushortx2*)(base + SWZ(c+e, r)) = ushortx2{ f2bf(x0), f2bf(x1) };
    }
}

// =============== fused kernel: one block per (bh, oct); 512 blocks x 256 threads ===============
// LDS 75,008 B -> exactly 2 blocks/CU -> all 512 blocks co-resident (spin-safe).
// Phase 1: oct KV snapshots into LDS. Phase 2: publish+flag+lookback. Phase 3: 4 output chunks.
__global__ __launch_bounds__(256, 2) void kF(const float* __restrict__ qp, const float* __restrict__ kp,
                                             const float* __restrict__ vp,
                                             unsigned short* __restrict__ spub, float* __restrict__ kpub,
                                             unsigned int* __restrict__ flags,
                                             float* __restrict__ outp)
{
    __shared__ __align__(16) unsigned short U[18432];       // phase1: kft/vtt dbuf | phase3: qf,kfx,vtt
    __shared__ __align__(16) unsigned short snapL[18432];   // [4][64][PAD] cumulative KV snapshots (bf16)
    __shared__ float ksnapL[4*DD];                          // cumulative K colsums per sub-chunk
    __shared__ float zr[DD];

    const int orig = blockIdx.x;
    const int o = orig >> 6, bh = orig & 63;                // same bh -> same orig%8 -> same XCD
    const int b = bh >> 4, h = bh & 15;
    const int t = threadIdx.x;
    const int w = t >> 6, lane = t & 63, quad = lane >> 4, lr = lane & 15;
    const int m0 = 16*w;
    const int sm = t >> 2, sd0 = (t & 3) << 4;              // S-ownership: thread owns S[sm][sd0..sd0+15]

    // ---------------- phase 1: oct-cumulative KV snapshots ----------------
    unsigned short* kftd0 = U;                 // [d][s] SWZ, 4608 ushorts
    unsigned short* kftd1 = U + 4608;
    unsigned short* vttd0 = U + 9216;          // [m][s] SWZ
    unsigned short* vttd1 = U + 13824;

    floatx4 acc[4];
#pragma unroll
    for (int dt = 0; dt < 4; ++dt) acc[dt] = floatx4{0.f,0.f,0.f,0.f};
    float ksa = 0.f;

    const int64_t gb0 = ((int64_t)(b*LL + o*256)*HH + h)*DD;
#pragma unroll
    for (int ii = 0; ii < 2; ++ii) {
        int flat = t + 256*ii;
        int l0s = (flat >> 4) * 2, col4 = (flat & 15) << 2;
        const float* gk = kp + gb0 + (int64_t)l0s*LSTR + col4;
        const float* gv = vp + gb0 + (int64_t)l0s*LSTR + col4;
        float4 ka = *(const float4*)gk, kb = *(const float4*)(gk + LSTR);
        float4 va = *(const float4*)gv, vb = *(const float4*)(gv + LSTR);
        st_tr<true >(kftd0, l0s, col4, ka, kb);
        st_tr<false>(vttd0, l0s, col4, va, vb);
    }
    __syncthreads();

#pragma unroll 1
    for (int sc = 0; sc < 4; ++sc) {
        unsigned short* kftp = (sc & 1) ? kftd1 : kftd0;
        unsigned short* vttp = (sc & 1) ? vttd1 : vttd0;
        unsigned short* kftn = (sc & 1) ? kftd0 : kftd1;
        unsigned short* vttn = (sc & 1) ? vttd0 : vttd1;
        float4 ka[2], kb[2], va[2], vb[2];
        if (sc < 3) {
            const int64_t gb = gb0 + (int64_t)(sc+1)*DD*LSTR;
#pragma unroll
            for (int ii = 0; ii < 2; ++ii) {
                int flat = t + 256*ii;
                int l0s = (flat >> 4) * 2, col4 = (flat & 15) << 2;
                const float* gk = kp + gb + (int64_t)l0s*LSTR + col4;
                const float* gv = vp + gb + (int64_t)l0s*LSTR + col4;
                ka[ii] = *(const float4*)gk; kb[ii] = *(const float4*)(gk + LSTR);
                va[ii] = *(const float4*)gv; vb[ii] = *(const float4*)(gv + LSTR);
            }
        }
#pragma unroll
        for (int kk = 0; kk < 2; ++kk) {
            bf16x8 a = ldf(vttp + SWZ(m0+lr, kk*32 + quad*8));
#pragma unroll
            for (int dt = 0; dt < 4; ++dt) {
                bf16x8 bbf = ldf(kftp + SWZ(dt*16+lr, kk*32 + quad*8));
                acc[dt] = __builtin_amdgcn_mfma_f32_16x16x32_bf16(a, bbf, acc[dt], 0, 0, 0);
            }
        }
        // cumulative snapshot -> snapL[sc] ([m][d], PAD rows)
        {
            unsigned short* so = snapL + sc*4608;
#pragma unroll
            for (int dt = 0; dt < 4; ++dt)
#pragma unroll
                for (int r = 0; r < 4; ++r)
                    so[(m0 + quad*4 + r)*PAD + dt*16 + lr] = f2bf(acc[dt][r]);
        }
        if (t < DD) {
#pragma unroll
            for (int jj = 0; jj < 8; ++jj) {
                ushortx8 u = *(const ushortx8*)(kftp + SWZ(t, jj*8));
#pragma unroll
                for (int e = 0; e < 8; ++e) ksa += bf2f(u[e]);
            }
            ksnapL[sc*DD + t] = ksa;
        }
        if (sc < 3) {
#pragma unroll
            for (int ii = 0; ii < 2; ++ii) {
                int flat = t + 256*ii;
                int l0s = (flat >> 4) * 2, col4 = (flat & 15) << 2;
                st_tr<true >(kftn, l0s, col4, ka[ii], kb[ii]);
                st_tr<false>(vttn, l0s, col4, va[ii], vb[ii]);
            }
        }
        __syncthreads();
    }

    // ---------------- phase 2: publish full-oct sum, flag, spin, lookback ----------------
    {
        const unsigned short* sp = snapL + 3*4608 + sm*PAD + sd0;
        ushortx8 a0 = *(const ushortx8*)sp;
        ushortx8 a1 = *(const ushortx8*)(sp + 8);
        unsigned short* po = spub + ((int64_t)(bh*8 + o))*4096 + sm*DD + sd0;
        *(ushortx8*)po = a0;
        *(ushortx8*)(po + 8) = a1;
        if (t < DD) kpub[((int64_t)(bh*8 + o))*DD + t] = ksnapL[3*DD + t];
    }
    __syncthreads();
    if (t == 0) {
        __threadfence();
        __hip_atomic_store(flags + bh*8 + o, MAGIC, __ATOMIC_RELEASE, __HIP_MEMORY_SCOPE_AGENT);
    }
    if (t < o) {
        while (__hip_atomic_load(flags + bh*8 + t, __ATOMIC_ACQUIRE, __HIP_MEMORY_SCOPE_AGENT) != MAGIC)
            __builtin_amdgcn_s_sleep(2);
    }
    __syncthreads();

    float S_base[16];
#pragma unroll
    for (int e = 0; e < 16; ++e) S_base[e] = 0.f;
#pragma unroll
    for (int op = 0; op < 7; ++op)
        if (op < o) {
            const unsigned short* sp = spub + ((int64_t)(bh*8 + op))*4096 + sm*DD + sd0;
            ushortx8 u0 = *(const ushortx8*)sp, u1 = *(const ushortx8*)(sp + 8);
#pragma unroll
            for (int e = 0; e < 8; ++e) { S_base[e] += bf2f(u0[e]); S_base[8+e] += bf2f(u1[e]); }
        }
    float ksb = 0.f;
    if (t < DD) {
#pragma unroll
        for (int op = 0; op < 7; ++op)
            if (op < o) ksb += kpub[((int64_t)(bh*8 + op))*DD + t];
    }

    // ---------------- phase 3: 4 output chunks (kC body), k/v now L2-hot ----------------
    unsigned short* qf  = U;                   // [l][d], 4608
    unsigned short* kfx = U + 4608;            // [s][d] + prefix rows, 80*PAD = 5760
    unsigned short* vtt = U + 10368;           // [m][s] SWZ, 4608
    unsigned short* sldp = snapL + 3*4608;     // S_j tile (slot 3 dead after publish)

#pragma unroll 1
    for (int j = 0; j < 4; ++j) {
        const int cg = o*4 + j;
        const int64_t gbase = ((int64_t)(b*LL + cg*DD)*HH + h)*DD;
        // ---- pre-barrier writes ----
        if (j == 0 && t < 135) *(ushortx8*)(kfx + 65*PAD + t*8) = ushortx8{0,0,0,0,0,0,0,0};
        if (t < DD) kfx[64*PAD + t] = f2bf(ksb + (j > 0 ? ksnapL[(j-1)*DD + t] : 0.f));
        {   // S_j = S_base + own snapshot j-1 -> sldp
            float sa[16];
#pragma unroll
            for (int e = 0; e < 16; ++e) sa[e] = S_base[e];
            if (j > 0) {
                const unsigned short* sp = snapL + (j-1)*4608 + sm*PAD + sd0;
                ushortx8 u0 = *(const ushortx8*)sp, u1 = *(const ushortx8*)(sp + 8);
#pragma unroll
                for (int e = 0; e < 8; ++e) { sa[e] += bf2f(u0[e]); sa[8+e] += bf2f(u1[e]); }
            }
            ushortx8 w0, w1;
#pragma unroll
            for (int e = 0; e < 8; ++e) { w0[e] = f2bf(sa[e]); w1[e] = f2bf(sa[8+e]); }
            *(ushortx8*)(sldp + sm*PAD + sd0)     = w0;
            *(ushortx8*)(sldp + sm*PAD + sd0 + 8) = w1;
        }
        // ---- stage q,k,v for this chunk (k,v from L2/L3) ----
#pragma unroll
        for (int i = 0; i < 2; ++i) {
            int flat = t + 256*i;
            int l0s = (flat >> 4) * 2, col = (flat & 15) << 2;
            const float* gq = qp + gbase + (int64_t)l0s*LSTR + col;
            const float* gk = kp + gbase + (int64_t)l0s*LSTR + col;
            const float* gv = vp + gbase + (int64_t)l0s*LSTR + col;
            float4 qa = *(const float4*)(gq), qb = *(const float4*)(gq + LSTR);
            float4 ka = *(const float4*)(gk), kb = *(const float4*)(gk + LSTR);
            float4 va = *(const float4*)(gv), vb = *(const float4*)(gv + LSTR);
            st_sd<true >(qf , l0s, col, qa, qb);
            st_sd<true >(kfx, l0s, col, ka, kb);
            st_tr<false>(vtt, l0s, col, va, vb);
        }
        __syncthreads();   // barrier A_j

        const int l0 = 16*w;
        bf16x8 aq0 = ldf(qf + (l0+lr)*PAD + quad*8);
        bf16x8 aq1 = ldf(qf + (l0+lr)*PAD + 32 + quad*8);

        // GEMM1: scores (4 tiles) + prefix-z tile (kfx rows 64-79)
        floatx4 sc5[5];
#pragma unroll
        for (int tt = 0; tt < 5; ++tt) sc5[tt] = floatx4{0.f,0.f,0.f,0.f};
#pragma unroll
        for (int kk = 0; kk < 2; ++kk) {
            bf16x8 aqk = kk ? aq1 : aq0;
#pragma unroll
            for (int tt = 0; tt < 5; ++tt) {
                bf16x8 bb = ldf(kfx + (tt*16+lr)*PAD + kk*32 + quad*8);
                sc5[tt] = __builtin_amdgcn_mfma_f32_16x16x32_bf16(aqk, bb, sc5[tt], 0, 0, 0);
            }
        }
        // causal mask + z + overlay masked scores onto own qf rows
        float zp[4] = {0.f,0.f,0.f,0.f};
#pragma unroll
        for (int tt = 0; tt < 4; ++tt)
#pragma unroll
            for (int r = 0; r < 4; ++r) {
                int row = l0 + quad*4 + r;
                int col = tt*16 + lr;
                float val = (col <= row) ? sc5[tt][r] : 0.f;
                zp[r] += val;
                qf[row*PAD + col] = f2bf(val);
            }
#pragma unroll
        for (int r = 0; r < 4; ++r) zp[r] += (lr == 0) ? sc5[4][r] : 0.f;
#pragma unroll
        for (int m = 1; m < 16; m <<= 1)
#pragma unroll
            for (int r = 0; r < 4; ++r) zp[r] += __shfl_xor(zp[r], m, 64);
        if (lr == 0)
#pragma unroll
            for (int r = 0; r < 4; ++r) zr[l0 + quad*4 + r] = 1.f / (zp[r] + EPSF);

        // GEMM2: out = Pmask * v + qf * S_j
        floatx4 oa[4];
#pragma unroll
        for (int mt = 0; mt < 4; ++mt) oa[mt] = floatx4{0.f,0.f,0.f,0.f};
#pragma unroll
        for (int kk = 0; kk < 2; ++kk) {
            bf16x8 a2 = ldf(qf + (l0+lr)*PAD + kk*32 + quad*8);    // own rows (intra-wave RAW)
#pragma unroll
            for (int mt = 0; mt < 4; ++mt) {
                bf16x8 bv = ldf(vtt + SWZ(mt*16+lr, kk*32 + quad*8));
                oa[mt] = __builtin_amdgcn_mfma_f32_16x16x32_bf16(a2, bv, oa[mt], 0, 0, 0);
            }
        }
#pragma unroll
        for (int kk = 0; kk < 2; ++kk) {
            bf16x8 aqk = kk ? aq1 : aq0;
#pragma unroll
            for (int mt = 0; mt < 4; ++mt) {
                bf16x8 bs = ldf(sldp + (mt*16+lr)*PAD + kk*32 + quad*8);
                oa[mt] = __builtin_amdgcn_mfma_f32_16x16x32_bf16(aqk, bs, oa[mt], 0, 0, 0);
            }
        }
#pragma unroll
        for (int r = 0; r < 4; ++r) {
            int row = l0 + quad*4 + r;
            float rz = zr[row];
#pragma unroll
            for (int mt = 0; mt < 4; ++mt)
                outp[gbase + (int64_t)row*LSTR + mt*16 + lr] = oa[mt][r] * rz;
        }
        __syncthreads();   // barrier B_j (protect qf/kfx/vtt/sldp before next chunk's writes)
    }
}

extern "C" void kernel_launch(void* const* d_in, const int* in_sizes, int n_in,
                              void* d_out, int out_size, void* d_ws, size_t ws_size,
                              hipStream_t stream) {
    const float* q = (const float*)d_in[0];
    const float* k = (const float*)d_in[1];
    const float* v = (const float*)d_in[2];
    float* out = (float*)d_out;
    char* ws = (char*)d_ws;
    unsigned short* spub = (unsigned short*)ws;                          // 512*4096 bf16 = 4 MiB
    float* kpub = (float*)(ws + (size_t)512*4096*2);                     // 512*64 fp32 = 128 KiB
    unsigned int* flags = (unsigned int*)(ws + (size_t)512*4096*2 + 512*64*4); // 512 u32 = 2 KiB
    kF<<<512, 256, 0, stream>>>(q, k, v, spub, kpub, flags, out);
}

// Round 7
// 157.526 us; speedup vs baseline: 1.1811x; 1.1811x over previous
//
#include <hip/hip_runtime.h>
#include <cstdint>

#define LL 2048
#define HH 16
#define DD 64
#define LSTR 1024      // H*D
#define EPSF 1e-6f
#define PAD 72         // ushorts per LDS row: 144 B = 16B-aligned
// swizzle for transposed-store tiles accessed with b128 frags
#define SWZ(row, off) ((row)*PAD + ((off) ^ ((((row)>>3)&7)<<3)))

typedef __bf16 bf16x8 __attribute__((ext_vector_type(8)));
typedef float floatx4 __attribute__((ext_vector_type(4)));
typedef unsigned short ushortx8 __attribute__((ext_vector_type(8)));
typedef unsigned short ushortx4 __attribute__((ext_vector_type(4)));
typedef unsigned short ushortx2 __attribute__((ext_vector_type(2)));

static __device__ __forceinline__ float fmap(float x){ return x > 0.f ? x + 1.f : __expf(x); }
static __device__ __forceinline__ unsigned short f2bf(float f){
    return __builtin_bit_cast(unsigned short, static_cast<__bf16>(f));   // RNE, 1 VALU op
}
static __device__ __forceinline__ float bf2f(unsigned short s){
    unsigned u = ((unsigned)s) << 16;
    return __builtin_bit_cast(float, u);
}
static __device__ __forceinline__ bf16x8 ldf(const unsigned short* p){
    return __builtin_bit_cast(bf16x8, *(const ushortx8*)p);
}

// store rows r, r+1 of an [s][d]-layout tile (bf16), optional feature map (unswizzled)
template<bool MAP>
static __device__ __forceinline__ void st_sd(unsigned short* base, int r, int c, float4 a, float4 b){
    if (MAP) {
        *(ushortx4*)(base + r*PAD + c)     = ushortx4{ f2bf(fmap(a.x)), f2bf(fmap(a.y)), f2bf(fmap(a.z)), f2bf(fmap(a.w)) };
        *(ushortx4*)(base + (r+1)*PAD + c) = ushortx4{ f2bf(fmap(b.x)), f2bf(fmap(b.y)), f2bf(fmap(b.z)), f2bf(fmap(b.w)) };
    } else {
        *(ushortx4*)(base + r*PAD + c)     = ushortx4{ f2bf(a.x), f2bf(a.y), f2bf(a.z), f2bf(a.w) };
        *(ushortx4*)(base + (r+1)*PAD + c) = ushortx4{ f2bf(b.x), f2bf(b.y), f2bf(b.z), f2bf(b.w) };
    }
}
// transposed store into a [d][s]- or [m][s]-layout tile (bf16), SWZ-swizzled
template<bool MAP>
static __device__ __forceinline__ void st_tr(unsigned short* base, int r, int c, float4 a, float4 b){
    float aa[4] = {a.x, a.y, a.z, a.w}, bb[4] = {b.x, b.y, b.z, b.w};
#pragma unroll
    for (int e = 0; e < 4; ++e) {
        float x0 = MAP ? fmap(aa[e]) : aa[e];
        float x1 = MAP ? fmap(bb[e]) : bb[e];
        *(ushortx2*)(base + SWZ(c+e, r)) = ushortx2{ f2bf(x0), f2bf(x1) };
    }
}

// ---------------- kA: per-oct KV accumulation with CUMULATIVE per-chunk snapshots ----------------
// 512 threads (8 waves, dt-split) -> 16 waves/CU at grid 512.
__global__ __launch_bounds__(512) void kA(const float* __restrict__ kp, const float* __restrict__ vp,
                                          unsigned short* __restrict__ snap, float* __restrict__ ksnap)
{
    __shared__ __align__(16) unsigned short kft[2][DD*PAD]; // kf^T [d][s] (SWZ)
    __shared__ __align__(16) unsigned short vtt[2][DD*PAD]; // v^T  [m][s] (SWZ)
    const int blk = blockIdx.x;                 // bh*8 + oct
    const int bh = blk >> 3, oct = blk & 7, b = bh >> 4, h = bh & 15;
    const int t = threadIdx.x;
    const int w = t >> 6, lane = t & 63, quad = lane >> 4, lr = lane & 15;
    const int m0 = 16*(w & 3), dth = (w >> 2) << 1;   // wave owns m-tile m0, dt tiles {dth, dth+1}
    const int l0s = (t >> 4) * 2, col4 = (t & 15) << 2;   // 512 staging slots

    floatx4 acc[2];
    acc[0] = floatx4{0.f,0.f,0.f,0.f};
    acc[1] = floatx4{0.f,0.f,0.f,0.f};
    float ksa = 0.f;

    const int64_t gb0 = ((int64_t)(b*LL + oct*256)*HH + h)*DD;
    // prologue: stage sub-chunk 0
    {
        const float* gk = kp + gb0 + (int64_t)l0s*LSTR + col4;
        const float* gv = vp + gb0 + (int64_t)l0s*LSTR + col4;
        float4 ka = *(const float4*)gk, kb = *(const float4*)(gk + LSTR);
        float4 va = *(const float4*)gv, vb = *(const float4*)(gv + LSTR);
        st_tr<true >(kft[0], l0s, col4, ka, kb);
        st_tr<false>(vtt[0], l0s, col4, va, vb);
    }
    __syncthreads();

#pragma unroll 1
    for (int sc = 0; sc < 4; ++sc) {
        const int p = sc & 1;
        float4 ka, kb, va, vb;
        if (sc < 3) {
            const int64_t gb = gb0 + (int64_t)(sc+1)*DD*LSTR;
            const float* gk = kp + gb + (int64_t)l0s*LSTR + col4;
            const float* gv = vp + gb + (int64_t)l0s*LSTR + col4;
            ka = *(const float4*)gk; kb = *(const float4*)(gk + LSTR);
            va = *(const float4*)gv; vb = *(const float4*)(gv + LSTR);
        }
        // accumulate KV^T[m][d] over this sub-chunk (this wave's 2 dt tiles)
#pragma unroll
        for (int kk = 0; kk < 2; ++kk) {
            bf16x8 a = ldf(vtt[p] + SWZ(m0+lr, kk*32 + quad*8));
#pragma unroll
            for (int dtl = 0; dtl < 2; ++dtl) {
                bf16x8 bbf = ldf(kft[p] + SWZ((dth+dtl)*16+lr, kk*32 + quad*8));
                acc[dtl] = __builtin_amdgcn_mfma_f32_16x16x32_bf16(a, bbf, acc[dtl], 0, 0, 0);
            }
        }
        // snapshot: cumulative KV (bf16) for chunks 0..sc
        {
            unsigned short* so = snap + ((int64_t)blk*4 + sc)*4096;
#pragma unroll
            for (int dtl = 0; dtl < 2; ++dtl)
#pragma unroll
                for (int r = 0; r < 4; ++r)
                    so[(m0 + quad*4 + r)*DD + (dth+dtl)*16 + lr] = f2bf(acc[dtl][r]);
        }
        // cumulative K colsum snapshot
        if (t < DD) {
#pragma unroll
            for (int jj = 0; jj < 8; ++jj) {
                ushortx8 u = *(const ushortx8*)(kft[p] + SWZ(t, jj*8));
#pragma unroll
                for (int e = 0; e < 8; ++e) ksa += bf2f(u[e]);
            }
            ksnap[((int64_t)blk*4 + sc)*DD + t] = ksa;
        }
        if (sc < 3) {
            st_tr<true >(kft[p^1], l0s, col4, ka, kb);
            st_tr<false>(vtt[p^1], l0s, col4, va, vb);
        }
        __syncthreads();
    }
}

// ---------------- kC v3: one block per 64-row chunk; 27.6 KB LDS; 2 barriers ----------------
__global__ __launch_bounds__(256, 4) void kC(const float* __restrict__ qp, const float* __restrict__ kp,
                                             const float* __restrict__ vp,
                                             const unsigned short* __restrict__ snap,
                                             const float* __restrict__ ksnap,
                                             float* __restrict__ outp)
{
    __shared__ __align__(16) unsigned short kfx[DD*PAD];  // kf [s][d]; after GEMM1: masked P [l][s]
    __shared__ __align__(16) unsigned short vtt[DD*PAD];  // v^T [m][s] (SWZ)
    __shared__ __align__(16) unsigned short sld[DD*PAD];  // prefix S [m][d] bf16
    const int bid = blockIdx.x;
    const int bh = bid >> 5, c = bid & 31, b = bh >> 4, h = bh & 15;
    const int o = c >> 2, j = c & 3;            // oct, chunk-within-oct
    const int t = threadIdx.x;
    const int w = t >> 6, lane = t & 63, quad = lane >> 4, lr = lane & 15;
    const int l0 = 16*w;
    const int64_t gbase = ((int64_t)(b*LL + c*DD)*HH + h)*DD;
    const int64_t so8 = (int64_t)bh*8;          // snapshot row base for this bh

    // ---- own-row Q: global -> fp32 regs (fmap), A-frag layout ----
    float qv[16];
    {
        const float* gq = qp + gbase + (int64_t)(l0+lr)*LSTR;
        float4 a0 = *(const float4*)(gq + quad*8);
        float4 a1 = *(const float4*)(gq + quad*8 + 4);
        float4 a2 = *(const float4*)(gq + 32 + quad*8);
        float4 a3 = *(const float4*)(gq + 32 + quad*8 + 4);
        qv[0]=fmap(a0.x); qv[1]=fmap(a0.y); qv[2]=fmap(a0.z); qv[3]=fmap(a0.w);
        qv[4]=fmap(a1.x); qv[5]=fmap(a1.y); qv[6]=fmap(a1.z); qv[7]=fmap(a1.w);
        qv[8]=fmap(a2.x); qv[9]=fmap(a2.y); qv[10]=fmap(a2.z); qv[11]=fmap(a2.w);
        qv[12]=fmap(a3.x); qv[13]=fmap(a3.y); qv[14]=fmap(a3.z); qv[15]=fmap(a3.w);
    }

    // ---- prefix S -> sld (per-thread owns S[sm][sd0..sd0+15]), flat predicated loads ----
    {
        const int sm = t >> 2, sd0 = (t & 3) << 4;
        float sa[16];
#pragma unroll
        for (int e = 0; e < 16; ++e) sa[e] = 0.f;
#pragma unroll
        for (int op = 0; op < 7; ++op)
            if (op < o) {
                const unsigned short* sp = snap + ((so8 + op)*4 + 3)*4096 + sm*DD + sd0;
                ushortx8 u0 = *(const ushortx8*)sp, u1 = *(const ushortx8*)(sp + 8);
#pragma unroll
                for (int e = 0; e < 8; ++e) { sa[e] += bf2f(u0[e]); sa[8+e] += bf2f(u1[e]); }
            }
        if (j > 0) {
            const unsigned short* sp = snap + ((so8 + o)*4 + (j-1))*4096 + sm*DD + sd0;
            ushortx8 u0 = *(const ushortx8*)sp, u1 = *(const ushortx8*)(sp + 8);
#pragma unroll
            for (int e = 0; e < 8; ++e) { sa[e] += bf2f(u0[e]); sa[8+e] += bf2f(u1[e]); }
        }
        ushortx8 w0, w1;
#pragma unroll
        for (int e = 0; e < 8; ++e) { w0[e] = f2bf(sa[e]); w1[e] = f2bf(sa[8+e]); }
        *(ushortx8*)(sld + sm*PAD + sd0)     = w0;
        *(ushortx8*)(sld + sm*PAD + sd0 + 8) = w1;
    }

    // ---- z prefix: per-lane fp32 dot q[row] . kpre, then wave reduce/transpose ----
    float zfull = 0.f;
    {
        float kp16[16];
#pragma unroll
        for (int e = 0; e < 16; ++e) kp16[e] = 0.f;
#pragma unroll
        for (int op = 0; op < 7; ++op)
            if (op < o) {
                const float* kb = ksnap + ((so8 + op)*4 + 3)*DD;
                float4 x0 = *(const float4*)(kb + quad*8);
                float4 x1 = *(const float4*)(kb + quad*8 + 4);
                float4 x2 = *(const float4*)(kb + 32 + quad*8);
                float4 x3 = *(const float4*)(kb + 32 + quad*8 + 4);
                kp16[0]+=x0.x; kp16[1]+=x0.y; kp16[2]+=x0.z; kp16[3]+=x0.w;
                kp16[4]+=x1.x; kp16[5]+=x1.y; kp16[6]+=x1.z; kp16[7]+=x1.w;
                kp16[8]+=x2.x; kp16[9]+=x2.y; kp16[10]+=x2.z; kp16[11]+=x2.w;
                kp16[12]+=x3.x; kp16[13]+=x3.y; kp16[14]+=x3.z; kp16[15]+=x3.w;
            }
        if (j > 0) {
            const float* kb = ksnap + ((so8 + o)*4 + (j-1))*DD;
            float4 x0 = *(const float4*)(kb + quad*8);
            float4 x1 = *(const float4*)(kb + quad*8 + 4);
            float4 x2 = *(const float4*)(kb + 32 + quad*8);
            float4 x3 = *(const float4*)(kb + 32 + quad*8 + 4);
            kp16[0]+=x0.x; kp16[1]+=x0.y; kp16[2]+=x0.z; kp16[3]+=x0.w;
            kp16[4]+=x1.x; kp16[5]+=x1.y; kp16[6]+=x1.z; kp16[7]+=x1.w;
            kp16[8]+=x2.x; kp16[9]+=x2.y; kp16[10]+=x2.z; kp16[11]+=x2.w;
            kp16[12]+=x3.x; kp16[13]+=x3.y; kp16[14]+=x3.z; kp16[15]+=x3.w;
        }
#pragma unroll
        for (int e = 0; e < 16; ++e) zfull += qv[e] * kp16[e];
        zfull += __shfl_xor(zfull, 16, 64);     // reduce across quads (same lr = same q-row)
        zfull += __shfl_xor(zfull, 32, 64);     // -> all quads' lane lr hold full dot for row l0+lr
    }

    // ---- pack Q A-frags ----
    bf16x8 aq0, aq1;
#pragma unroll
    for (int e = 0; e < 8; ++e) { aq0[e] = (__bf16)qv[e]; aq1[e] = (__bf16)qv[8+e]; }

    // ---- stage k, v for own 64 rows ----
#pragma unroll
    for (int i = 0; i < 2; ++i) {
        int flat = t + 256*i;
        int l0s = (flat >> 4) * 2, col = (flat & 15) << 2;
        const float* gk = kp + gbase + (int64_t)l0s*LSTR + col;
        const float* gv = vp + gbase + (int64_t)l0s*LSTR + col;
        float4 ka = *(const float4*)(gk), kb = *(const float4*)(gk + LSTR);
        float4 va = *(const float4*)(gv), vb = *(const float4*)(gv + LSTR);
        st_sd<true >(kfx, l0s, col, ka, kb);
        st_tr<false>(vtt, l0s, col, va, vb);
    }
    __syncthreads();   // barrier A

    // ---- GEMM1: scores = qf * kf^T (4 tiles) ----
    floatx4 sc4[4];
#pragma unroll
    for (int tt = 0; tt < 4; ++tt) sc4[tt] = floatx4{0.f,0.f,0.f,0.f};
#pragma unroll
    for (int kk = 0; kk < 2; ++kk) {
        bf16x8 aqk = kk ? aq1 : aq0;
#pragma unroll
        for (int tt = 0; tt < 4; ++tt) {
            bf16x8 bb = ldf(kfx + (tt*16+lr)*PAD + kk*32 + quad*8);
            sc4[tt] = __builtin_amdgcn_mfma_f32_16x16x32_bf16(aqk, bb, sc4[tt], 0, 0, 0);
        }
    }
    __syncthreads();   // barrier B: kfx (k data) dead, becomes P scratch

    // ---- causal mask + z rowsums; overlay masked P onto kfx own rows ([l][s]) ----
    float zp[4] = {0.f,0.f,0.f,0.f};
#pragma unroll
    for (int tt = 0; tt < 4; ++tt)
#pragma unroll
        for (int r = 0; r < 4; ++r) {
            int row = l0 + quad*4 + r;
            int col = tt*16 + lr;
            float val = (col <= row) ? sc4[tt][r] : 0.f;
            zp[r] += val;
            kfx[row*PAD + col] = f2bf(val);
        }
#pragma unroll
    for (int m = 1; m < 16; m <<= 1)
#pragma unroll
        for (int r = 0; r < 4; ++r) zp[r] += __shfl_xor(zp[r], m, 64);
    float rz[4];
#pragma unroll
    for (int r = 0; r < 4; ++r) {
        zp[r] += __shfl(zfull, quad*20 + r, 64);   // z-prefix for row l0+quad*4+r
        rz[r] = 1.f / (zp[r] + EPSF);
    }

    // ---- GEMM2: out = Pmask * v + qf * S ----
    floatx4 oa[4];
#pragma unroll
    for (int mt = 0; mt < 4; ++mt) oa[mt] = floatx4{0.f,0.f,0.f,0.f};
#pragma unroll
    for (int kk = 0; kk < 2; ++kk) {
        bf16x8 a2 = ldf(kfx + (l0+lr)*PAD + kk*32 + quad*8);   // own rows (intra-wave RAW)
#pragma unroll
        for (int mt = 0; mt < 4; ++mt) {
            bf16x8 bv = ldf(vtt + SWZ(mt*16+lr, kk*32 + quad*8));
            oa[mt] = __builtin_amdgcn_mfma_f32_16x16x32_bf16(a2, bv, oa[mt], 0, 0, 0);
        }
    }
#pragma unroll
    for (int kk = 0; kk < 2; ++kk) {
        bf16x8 aqk = kk ? aq1 : aq0;
#pragma unroll
        for (int mt = 0; mt < 4; ++mt) {
            bf16x8 bs = ldf(sld + (mt*16+lr)*PAD + kk*32 + quad*8);
            oa[mt] = __builtin_amdgcn_mfma_f32_16x16x32_bf16(aqk, bs, oa[mt], 0, 0, 0);
        }
    }
#pragma unroll
    for (int r = 0; r < 4; ++r) {
        int row = l0 + quad*4 + r;
#pragma unroll
        for (int mt = 0; mt < 4; ++mt)
            outp[gbase + (int64_t)row*LSTR + mt*16 + lr] = oa[mt][r] * rz[r];
    }
}

extern "C" void kernel_launch(void* const* d_in, const int* in_sizes, int n_in,
                              void* d_out, int out_size, void* d_ws, size_t ws_size,
                              hipStream_t stream) {
    const float* q = (const float*)d_in[0];
    const float* k = (const float*)d_in[1];
    const float* v = (const float*)d_in[2];
    float* out = (float*)d_out;
    char* ws = (char*)d_ws;
    unsigned short* snap = (unsigned short*)ws;                       // 512*4*4096 bf16 = 16 MiB
    float* ksnap = (float*)(ws + (size_t)512*4*4096*2);               // 512*4*64 fp32 = 512 KiB
    kA<<<512,  512, 0, stream>>>(k, v, snap, ksnap);
    kC<<<2048, 256, 0, stream>>>(q, k, v, snap, ksnap, out);
}

// Round 8
// 155.354 us; speedup vs baseline: 1.1976x; 1.0140x over previous
//
#include <hip/hip_runtime.h>
#include <cstdint>

#define LL 2048
#define HH 16
#define DD 64
#define LSTR 1024      // H*D
#define EPSF 1e-6f
#define PAD 72         // ushorts per LDS row: 144 B = 16B-aligned; 2-way (free) on b128 frags
// swizzle for transposed-store tiles accessed with b128 frags
#define SWZ(row, off) ((row)*PAD + ((off) ^ ((((row)>>3)&7)<<3)))

typedef __bf16 bf16x8 __attribute__((ext_vector_type(8)));
typedef float floatx4 __attribute__((ext_vector_type(4)));
typedef unsigned short ushortx8 __attribute__((ext_vector_type(8)));
typedef unsigned short ushortx4 __attribute__((ext_vector_type(4)));
typedef unsigned short ushortx2 __attribute__((ext_vector_type(2)));

static __device__ __forceinline__ float fmap(float x){ return x > 0.f ? x + 1.f : __expf(x); }
static __device__ __forceinline__ unsigned short f2bf(float f){
    return __builtin_bit_cast(unsigned short, static_cast<__bf16>(f));   // RNE, 1 VALU op
}
static __device__ __forceinline__ float bf2f(unsigned short s){
    unsigned u = ((unsigned)s) << 16;
    return __builtin_bit_cast(float, u);
}
static __device__ __forceinline__ bf16x8 ldf(const unsigned short* p){
    return __builtin_bit_cast(bf16x8, *(const ushortx8*)p);
}

// store rows r, r+1 of an [s][d]-layout tile (bf16), optional feature map (unswizzled)
template<bool MAP>
static __device__ __forceinline__ void st_sd(unsigned short* base, int r, int c, float4 a, float4 b){
    if (MAP) {
        *(ushortx4*)(base + r*PAD + c)     = ushortx4{ f2bf(fmap(a.x)), f2bf(fmap(a.y)), f2bf(fmap(a.z)), f2bf(fmap(a.w)) };
        *(ushortx4*)(base + (r+1)*PAD + c) = ushortx4{ f2bf(fmap(b.x)), f2bf(fmap(b.y)), f2bf(fmap(b.z)), f2bf(fmap(b.w)) };
    } else {
        *(ushortx4*)(base + r*PAD + c)     = ushortx4{ f2bf(a.x), f2bf(a.y), f2bf(a.z), f2bf(a.w) };
        *(ushortx4*)(base + (r+1)*PAD + c) = ushortx4{ f2bf(b.x), f2bf(b.y), f2bf(b.z), f2bf(b.w) };
    }
}
// transposed store into a [d][s]- or [m][s]-layout tile (bf16), SWZ-swizzled
template<bool MAP>
static __device__ __forceinline__ void st_tr(unsigned short* base, int r, int c, float4 a, float4 b){
    float aa[4] = {a.x, a.y, a.z, a.w}, bb[4] = {b.x, b.y, b.z, b.w};
#pragma unroll
    for (int e = 0; e < 4; ++e) {
        float x0 = MAP ? fmap(aa[e]) : aa[e];
        float x1 = MAP ? fmap(bb[e]) : bb[e];
        *(ushortx2*)(base + SWZ(c+e, r)) = ushortx2{ f2bf(x0), f2bf(x1) };
    }
}

// ---------------- kA: per-oct KV accumulation with CUMULATIVE per-chunk snapshots ----------------
// 512 threads (8 waves, dt-split). Block remap: all octs of one bh on one XCD (XCD = bh%8).
__global__ __launch_bounds__(512) void kA(const float* __restrict__ kp, const float* __restrict__ vp,
                                          unsigned short* __restrict__ snap, float* __restrict__ ksnap)
{
    __shared__ __align__(16) unsigned short kft[2][DD*PAD]; // kf^T [d][s] (SWZ)
    __shared__ __align__(16) unsigned short vtt[2][DD*PAD]; // v^T  [m][s] (SWZ)
    const int orig = blockIdx.x;
    const int oct = orig >> 6, bh = orig & 63, b = bh >> 4, h = bh & 15;
    const int64_t sblk = (int64_t)bh*8 + oct;   // snap layout index (by bh,oct)
    const int t = threadIdx.x;
    const int w = t >> 6, lane = t & 63, quad = lane >> 4, lr = lane & 15;
    const int m0 = 16*(w & 3), dth = (w >> 2) << 1;   // wave owns m-tile m0, dt tiles {dth, dth+1}
    const int l0s = (t >> 4) * 2, col4 = (t & 15) << 2;   // 512 staging slots

    floatx4 acc[2];
    acc[0] = floatx4{0.f,0.f,0.f,0.f};
    acc[1] = floatx4{0.f,0.f,0.f,0.f};
    float ksa = 0.f;

    const int64_t gb0 = ((int64_t)(b*LL + oct*256)*HH + h)*DD;
    // prologue: stage sub-chunk 0
    {
        const float* gk = kp + gb0 + (int64_t)l0s*LSTR + col4;
        const float* gv = vp + gb0 + (int64_t)l0s*LSTR + col4;
        float4 ka = *(const float4*)gk, kb = *(const float4*)(gk + LSTR);
        float4 va = *(const float4*)gv, vb = *(const float4*)(gv + LSTR);
        st_tr<true >(kft[0], l0s, col4, ka, kb);
        st_tr<false>(vtt[0], l0s, col4, va, vb);
    }
    __syncthreads();

#pragma unroll 1
    for (int sc = 0; sc < 4; ++sc) {
        const int p = sc & 1;
        float4 ka, kb, va, vb;
        if (sc < 3) {
            const int64_t gb = gb0 + (int64_t)(sc+1)*DD*LSTR;
            const float* gk = kp + gb + (int64_t)l0s*LSTR + col4;
            const float* gv = vp + gb + (int64_t)l0s*LSTR + col4;
            ka = *(const float4*)gk; kb = *(const float4*)(gk + LSTR);
            va = *(const float4*)gv; vb = *(const float4*)(gv + LSTR);
        }
        // accumulate KV^T[m][d] over this sub-chunk (this wave's 2 dt tiles)
#pragma unroll
        for (int kk = 0; kk < 2; ++kk) {
            bf16x8 a = ldf(vtt[p] + SWZ(m0+lr, kk*32 + quad*8));
#pragma unroll
            for (int dtl = 0; dtl < 2; ++dtl) {
                bf16x8 bbf = ldf(kft[p] + SWZ((dth+dtl)*16+lr, kk*32 + quad*8));
                acc[dtl] = __builtin_amdgcn_mfma_f32_16x16x32_bf16(a, bbf, acc[dtl], 0, 0, 0);
            }
        }
        // snapshot: cumulative KV (bf16) for chunks 0..sc
        {
            unsigned short* so = snap + (sblk*4 + sc)*4096;
#pragma unroll
            for (int dtl = 0; dtl < 2; ++dtl)
#pragma unroll
                for (int r = 0; r < 4; ++r)
                    so[(m0 + quad*4 + r)*DD + (dth+dtl)*16 + lr] = f2bf(acc[dtl][r]);
        }
        // cumulative K colsum snapshot
        if (t < DD) {
#pragma unroll
            for (int jj = 0; jj < 8; ++jj) {
                ushortx8 u = *(const ushortx8*)(kft[p] + SWZ(t, jj*8));
#pragma unroll
                for (int e = 0; e < 8; ++e) ksa += bf2f(u[e]);
            }
            ksnap[(sblk*4 + sc)*DD + t] = ksa;
        }
        if (sc < 3) {
            st_tr<true >(kft[p^1], l0s, col4, ka, kb);
            st_tr<false>(vtt[p^1], l0s, col4, va, vb);
        }
        __syncthreads();
    }
}

// ---------------- kD: per-oct output kernel, 4 independent chunks, double-buffered ----------------
// 512 blocks x 512 threads = 2 blocks/CU (LDS 75 KB). No serial S chain; S from snapshots.
__global__ __launch_bounds__(512, 2) void kD(const float* __restrict__ qp, const float* __restrict__ kp,
                                             const float* __restrict__ vp,
                                             const unsigned short* __restrict__ snap,
                                             const float* __restrict__ ksnap,
                                             float* __restrict__ outp)
{
    __shared__ __align__(16) unsigned short qls[2][DD*PAD]; // qf [l][d] dbuf
    __shared__ __align__(16) unsigned short kfx[2][DD*PAD]; // kf [s][d] dbuf
    __shared__ __align__(16) unsigned short vtt[2][DD*PAD]; // v^T [m][s] dbuf (SWZ)
    __shared__ __align__(16) unsigned short sct[DD*PAD];    // masked P [l][s]
    __shared__ __align__(16) unsigned short sld[DD*PAD];    // prefix S [m][d] bf16
    __shared__ float zp2[2][DD];
    __shared__ float kzb[DD];      // cross-oct colsum prefix (fp32)
    __shared__ float kzs[2][DD];   // kzb + own-oct cumulative colsum (per chunk, dbuf)

    const int orig = blockIdx.x;
    const int o = orig >> 6, bh = orig & 63, b = bh >> 4, h = bh & 15;  // XCD = bh%8
    const int t = threadIdx.x;
    const int w = t >> 6, lane = t & 63, quad = lane >> 4, lr = lane & 15;
    const int wi = w >> 1, wj = w & 1;          // row-tile (16 rows), s/m half
    const int l0 = 16*wi;
    const int l0s = (t >> 4) * 2, col4 = (t & 15) << 2;   // staging slots
    const int sm = t >> 3, sd0 = (t & 7) << 3;  // S ownership: 8 elems/thread
    const int64_t bhb = ((int64_t)b*LL*HH + h)*DD;
    const int64_t sb8 = (int64_t)bh*8;

    // ---- prologue: S_base, kzb, stage chunk 0 ----
    float sbase[8];
#pragma unroll
    for (int e = 0; e < 8; ++e) sbase[e] = 0.f;
#pragma unroll
    for (int op = 0; op < 7; ++op)
        if (op < o) {
            ushortx8 u = *(const ushortx8*)(snap + ((sb8+op)*4 + 3)*4096 + sm*DD + sd0);
#pragma unroll
            for (int e = 0; e < 8; ++e) sbase[e] += bf2f(u[e]);
        }
    {
        ushortx8 w0;
#pragma unroll
        for (int e = 0; e < 8; ++e) w0[e] = f2bf(sbase[e]);
        *(ushortx8*)(sld + sm*PAD + sd0) = w0;   // S_0
    }
    if (t < 16) {
        float a0=0.f, a1=0.f, a2=0.f, a3=0.f;
#pragma unroll
        for (int op = 0; op < 7; ++op)
            if (op < o) {
                float4 x = *(const float4*)(ksnap + ((sb8+op)*4 + 3)*DD + t*4);
                a0 += x.x; a1 += x.y; a2 += x.z; a3 += x.w;
            }
        *(float4*)(kzb + t*4) = float4{a0,a1,a2,a3};
    }
    {
        const int64_t gb = bhb + (int64_t)(o*4)*DD*LSTR;
        const float* gq = qp + gb + (int64_t)l0s*LSTR + col4;
        const float* gk = kp + gb + (int64_t)l0s*LSTR + col4;
        const float* gv = vp + gb + (int64_t)l0s*LSTR + col4;
        float4 q0 = *(const float4*)gq, q1 = *(const float4*)(gq + LSTR);
        float4 k0 = *(const float4*)gk, k1 = *(const float4*)(gk + LSTR);
        float4 v0 = *(const float4*)gv, v1 = *(const float4*)(gv + LSTR);
        st_sd<true >(qls[0], l0s, col4, q0, q1);
        st_sd<true >(kfx[0], l0s, col4, k0, k1);
        st_tr<false>(vtt[0], l0s, col4, v0, v1);
    }
    __syncthreads();

    ushortx8 usn = ushortx8{0,0,0,0,0,0,0,0};   // carried own-oct snapshot for next S
    float4 cq0, cq1, ck0, ck1, cv0, cv1;        // carried next-chunk q,k,v

#pragma unroll 1
    for (int j = 0; j < 4; ++j) {
        const int p = j & 1;
        const int64_t gb = bhb + (int64_t)(o*4 + j)*DD*LSTR;
        // ---- top: S_j (j>=1), aq frags, z-prefix dot ----
        if (j > 0) {
            ushortx8 w0;
#pragma unroll
            for (int e = 0; e < 8; ++e) w0[e] = f2bf(sbase[e] + bf2f(usn[e]));
            *(ushortx8*)(sld + sm*PAD + sd0) = w0;
        }
        bf16x8 aq0 = ldf(qls[p] + (l0+lr)*PAD + quad*8);
        bf16x8 aq1 = ldf(qls[p] + (l0+lr)*PAD + 32 + quad*8);
        float zfull = 0.f;
        {
            const float* kc = (j == 0) ? kzb : kzs[j & 1];
#pragma unroll
            for (int e = 0; e < 8; ++e) zfull += (float)aq0[e] * kc[quad*8 + e];
#pragma unroll
            for (int e = 0; e < 8; ++e) zfull += (float)aq1[e] * kc[32 + quad*8 + e];
            zfull += __shfl_xor(zfull, 16, 64);
            zfull += __shfl_xor(zfull, 32, 64);   // all lanes: full prefix dot for row l0+lr
        }
        // ---- issue next-chunk loads (retire during compute) ----
        if (j < 3) {
            const int64_t gn = bhb + (int64_t)(o*4 + j + 1)*DD*LSTR;
            const float* gq = qp + gn + (int64_t)l0s*LSTR + col4;
            const float* gk = kp + gn + (int64_t)l0s*LSTR + col4;
            const float* gv = vp + gn + (int64_t)l0s*LSTR + col4;
            cq0 = *(const float4*)gq; cq1 = *(const float4*)(gq + LSTR);
            ck0 = *(const float4*)gk; ck1 = *(const float4*)(gk + LSTR);
            cv0 = *(const float4*)gv; cv1 = *(const float4*)(gv + LSTR);
            usn = *(const ushortx8*)(snap + ((sb8+o)*4 + j)*4096 + sm*DD + sd0);
            if (t < 16) {
                float4 x = *(const float4*)(ksnap + ((sb8+o)*4 + j)*DD + t*4);
                float4 zb = *(const float4*)(kzb + t*4);
                *(float4*)(kzs[(j+1)&1] + t*4) = float4{zb.x+x.x, zb.y+x.y, zb.z+x.z, zb.w+x.w};
            }
        }
        // ---- GEMM1: scores for this wave's s-half ----
        floatx4 s0 = floatx4{0.f,0.f,0.f,0.f}, s1 = floatx4{0.f,0.f,0.f,0.f};
#pragma unroll
        for (int kk = 0; kk < 2; ++kk) {
            bf16x8 aqk = kk ? aq1 : aq0;
            bf16x8 b0 = ldf(kfx[p] + ((2*wj+0)*16+lr)*PAD + kk*32 + quad*8);
            bf16x8 b1 = ldf(kfx[p] + ((2*wj+1)*16+lr)*PAD + kk*32 + quad*8);
            s0 = __builtin_amdgcn_mfma_f32_16x16x32_bf16(aqk, b0, s0, 0, 0, 0);
            s1 = __builtin_amdgcn_mfma_f32_16x16x32_bf16(aqk, b1, s1, 0, 0, 0);
        }
        // ---- causal mask + overlay to sct + z partials ----
        float zpv[4] = {0.f,0.f,0.f,0.f};
#pragma unroll
        for (int tt = 0; tt < 2; ++tt) {
            int colb = (2*wj+tt)*16 + lr;
            floatx4 sv = tt ? s1 : s0;
#pragma unroll
            for (int r = 0; r < 4; ++r) {
                int row = l0 + quad*4 + r;
                float val = (colb <= row) ? sv[r] : 0.f;
                zpv[r] += val;
                sct[row*PAD + colb] = f2bf(val);
            }
        }
#pragma unroll
        for (int m = 1; m < 16; m <<= 1)
#pragma unroll
            for (int r = 0; r < 4; ++r) zpv[r] += __shfl_xor(zpv[r], m, 64);
        float zadd[4];
#pragma unroll
        for (int r = 0; r < 4; ++r) zadd[r] = __shfl(zfull, quad*20 + r, 64);
        if (lr == 0) {
#pragma unroll
            for (int r = 0; r < 4; ++r)
                zp2[wj][l0 + quad*4 + r] = zpv[r] + (wj == 0 ? zadd[r] : 0.f);
        }
        __syncthreads();   // BARRIER1: sct, sld, zp2 visible

        // ---- GEMM2: out = Pmask * v + qf * S_j ----
        floatx4 oa0 = floatx4{0.f,0.f,0.f,0.f}, oa1 = floatx4{0.f,0.f,0.f,0.f};
#pragma unroll
        for (int kk = 0; kk < 2; ++kk) {
            bf16x8 a2  = ldf(sct + (l0+lr)*PAD + kk*32 + quad*8);
            bf16x8 bv0 = ldf(vtt[p] + SWZ((2*wj+0)*16+lr, kk*32 + quad*8));
            bf16x8 bv1 = ldf(vtt[p] + SWZ((2*wj+1)*16+lr, kk*32 + quad*8));
            oa0 = __builtin_amdgcn_mfma_f32_16x16x32_bf16(a2, bv0, oa0, 0, 0, 0);
            oa1 = __builtin_amdgcn_mfma_f32_16x16x32_bf16(a2, bv1, oa1, 0, 0, 0);
        }
#pragma unroll
        for (int kk = 0; kk < 2; ++kk) {
            bf16x8 aqk = kk ? aq1 : aq0;
            bf16x8 bs0 = ldf(sld + ((2*wj+0)*16+lr)*PAD + kk*32 + quad*8);
            bf16x8 bs1 = ldf(sld + ((2*wj+1)*16+lr)*PAD + kk*32 + quad*8);
            oa0 = __builtin_amdgcn_mfma_f32_16x16x32_bf16(aqk, bs0, oa0, 0, 0, 0);
            oa1 = __builtin_amdgcn_mfma_f32_16x16x32_bf16(aqk, bs1, oa1, 0, 0, 0);
        }
#pragma unroll
        for (int r = 0; r < 4; ++r) {
            int row = l0 + quad*4 + r;
            float rz = 1.f / (zp2[0][row] + zp2[1][row] + EPSF);
            outp[gb + (int64_t)row*LSTR + (2*wj+0)*16 + lr] = oa0[r] * rz;
            outp[gb + (int64_t)row*LSTR + (2*wj+1)*16 + lr] = oa1[r] * rz;
        }
        // ---- stage next chunk from carried regs ----
        if (j < 3) {
            st_sd<true >(qls[p^1], l0s, col4, cq0, cq1);
            st_sd<true >(kfx[p^1], l0s, col4, ck0, ck1);
            st_tr<false>(vtt[p^1], l0s, col4, cv0, cv1);
        }
        __syncthreads();   // BARRIER2: next buffers ready; all reads of this chunk done
    }
}

extern "C" void kernel_launch(void* const* d_in, const int* in_sizes, int n_in,
                              void* d_out, int out_size, void* d_ws, size_t ws_size,
                              hipStream_t stream) {
    const float* q = (const float*)d_in[0];
    const float* k = (const float*)d_in[1];
    const float* v = (const float*)d_in[2];
    float* out = (float*)d_out;
    char* ws = (char*)d_ws;
    unsigned short* snap = (unsigned short*)ws;                       // 512*4*4096 bf16 = 16 MiB
    float* ksnap = (float*)(ws + (size_t)512*4*4096*2);               // 512*4*64 fp32 = 512 KiB
    kA<<<512, 512, 0, stream>>>(k, v, snap, ksnap);
    kD<<<512, 512, 0, stream>>>(q, k, v, snap, ksnap, out);
}